// Round 6
// baseline (730.833 us; speedup 1.0000x reference)
//
#include <hip/hip_runtime.h>

#define N_OPE 2048
#define N_MAC 1024
#define DIM   64
#define KOUT  128
#define NB    32

typedef __attribute__((ext_vector_type(8))) short short8;
typedef __attribute__((ext_vector_type(4))) float floatx4;

static __device__ __forceinline__ unsigned short f2bf(float f) {
    unsigned int u = __builtin_bit_cast(unsigned int, f);
    u += 0x7fffu + ((u >> 16) & 1u);   // round-to-nearest-even
    return (unsigned short)(u >> 16);
}
static __device__ __forceinline__ float bf2f(unsigned short h) {
    unsigned int u = ((unsigned int)h) << 16;
    return __builtin_bit_cast(float, u);
}

// ---------------- kernel 0: bit-pack the adjacency mask ----------------
// pk[b][mc][o] : bit j = adj[bidx[b]][o][mc*32+j]  (adj values are 0/1 -> v&1)
// Each block streams a contiguous 256 KiB tile (64 rows) sequentially, packs,
// LDS-transposes, writes coalesced. 256 MiB read at streaming BW, 8 MiB write.
__global__ __launch_bounds__(256) void k_pack(const int* __restrict__ adj,
        const int* __restrict__ bidx, unsigned* __restrict__ pk)
{
    __shared__ unsigned P[32][65];
    int bid = blockIdx.x;                     // 1024 = 32 b x 32 o-tiles
    int b = bid >> 5, obase = (bid & 31) * 64;
    int t = threadIdx.x;
    const int* adjr = adj + (size_t)bidx[b] * (N_OPE * N_MAC) + (size_t)obase * N_MAC;

    #pragma unroll
    for (int w = 0; w < 8; ++w) {
        int idx = w * 256 + t;
        int r = idx >> 5, mc = idx & 31;
        const int4* p = (const int4*)(adjr + r * N_MAC + mc * 32);
        unsigned word = 0;
        #pragma unroll
        for (int k = 0; k < 8; ++k) {
            int4 v = p[k];
            word |= (unsigned)(v.x & 1) << (4 * k);
            word |= (unsigned)(v.y & 1) << (4 * k + 1);
            word |= (unsigned)(v.z & 1) << (4 * k + 2);
            word |= (unsigned)(v.w & 1) << (4 * k + 3);
        }
        P[mc][r] = word;
    }
    __syncthreads();
    unsigned* dst = pk + ((size_t)b * 32) * N_OPE + obase;
    int oi = t & 63;
    #pragma unroll
    for (int ww = 0; ww < 8; ++ww) {
        int mc = ww * 4 + (t >> 6);
        dst[(size_t)mc * N_OPE + oi] = P[mc][oi];
    }
}

// ---------------- kernel 1: h_ope via 3-term bf16 MFMA -> h_f (fragment-major),
//                  plus pq[o] = (exp(attn_ope), exp(0.2*attn_ope)) ----------------
__global__ __launch_bounds__(256, 2) void k_ope(const float* __restrict__ feat,
        const float* __restrict__ w, const float* __restrict__ alpha,
        unsigned short* __restrict__ h_f, float2* __restrict__ pq)
{
    int wid = threadIdx.x >> 6, lane = threadIdx.x & 63;
    int L = lane & 15, q = lane >> 4;
    int base = blockIdx.x * 128 + wid * 32;
    int b = base >> 11;
    int o0w = base & (N_OPE - 1);

    float fA[2][2][8];
    #pragma unroll
    for (int mf = 0; mf < 2; ++mf) {
        const float* fr = feat + (size_t)(base + mf * 16 + L) * DIM + q * 8;
        #pragma unroll
        for (int ks = 0; ks < 2; ++ks) {
            float4 v0 = *(const float4*)(fr + ks * 32);
            float4 v1 = *(const float4*)(fr + ks * 32 + 4);
            fA[mf][ks][0] = v0.x; fA[mf][ks][1] = v0.y; fA[mf][ks][2] = v0.z; fA[mf][ks][3] = v0.w;
            fA[mf][ks][4] = v1.x; fA[mf][ks][5] = v1.y; fA[mf][ks][6] = v1.z; fA[mf][ks][7] = v1.w;
        }
    }

    short8 Ah[2][2], Al[2][2];
    #pragma unroll
    for (int mf = 0; mf < 2; ++mf)
        #pragma unroll
        for (int ks = 0; ks < 2; ++ks)
            #pragma unroll
            for (int j = 0; j < 8; ++j) {
                float x = fA[mf][ks][j];
                unsigned short h = f2bf(x);
                Ah[mf][ks][j] = (short)h;
                Al[mf][ks][j] = (short)f2bf(x - bf2f(h));
            }

    floatx4 C[2][8];
    #pragma unroll
    for (int mf = 0; mf < 2; ++mf)
        #pragma unroll
        for (int nf = 0; nf < 8; ++nf) C[mf][nf] = (floatx4)0.f;

    #pragma unroll
    for (int ks = 0; ks < 2; ++ks) {
        #pragma unroll
        for (int nf = 0; nf < 8; ++nf) {
            const float* wp = w + (size_t)(nf * 16 + L) * DIM + ks * 32 + q * 8;
            float4 u0 = *(const float4*)(wp);
            float4 u1 = *(const float4*)(wp + 4);
            float bw[8] = {u0.x, u0.y, u0.z, u0.w, u1.x, u1.y, u1.z, u1.w};
            short8 Bh, Bl;
            #pragma unroll
            for (int j = 0; j < 8; ++j) {
                unsigned short h = f2bf(bw[j]);
                Bh[j] = (short)h;
                Bl[j] = (short)f2bf(bw[j] - bf2f(h));
            }
            #pragma unroll
            for (int mf = 0; mf < 2; ++mf) {
                C[mf][nf] = __builtin_amdgcn_mfma_f32_16x16x32_bf16(Ah[mf][ks], Bh, C[mf][nf], 0, 0, 0);
                C[mf][nf] = __builtin_amdgcn_mfma_f32_16x16x32_bf16(Al[mf][ks], Bh, C[mf][nf], 0, 0, 0);
                C[mf][nf] = __builtin_amdgcn_mfma_f32_16x16x32_bf16(Ah[mf][ks], Bl, C[mf][nf], 0, 0, 0);
            }
        }
    }

    float alf[8];
    #pragma unroll
    for (int nf = 0; nf < 8; ++nf) alf[nf] = alpha[nf * 16 + L];
    #pragma unroll
    for (int mf = 0; mf < 2; ++mf) {
        #pragma unroll
        for (int r = 0; r < 4; ++r) {
            float s = 0.f;
            #pragma unroll
            for (int nf = 0; nf < 8; ++nf) s = fmaf(C[mf][nf][r], alf[nf], s);
            s += __shfl_xor(s, 1); s += __shfl_xor(s, 2);
            s += __shfl_xor(s, 4); s += __shfl_xor(s, 8);
            if (L == 0)
                pq[base + mf * 16 + q * 4 + r] = make_float2(__expf(s), __expf(0.2f * s));
        }
    }

    __shared__ unsigned short T[4][128 * 40];
    #pragma unroll
    for (int mf = 0; mf < 2; ++mf)
        #pragma unroll
        for (int nf = 0; nf < 8; ++nf)
            #pragma unroll
            for (int r = 0; r < 4; ++r)
                T[wid][(nf * 16 + L) * 40 + mf * 16 + q * 4 + r] = f2bf(C[mf][nf][r]);
    __syncthreads();

    int oc = o0w >> 5;
    unsigned short* dst = h_f + ((((size_t)b * 64 + oc) * 8) * 64 + lane) * 8;
    #pragma unroll
    for (int nf = 0; nf < 8; ++nf) {
        short8 v = *(const short8*)&T[wid][(nf * 16 + L) * 40 + q * 8];
        *(short8*)(dst + (size_t)nf * 512) = v;
    }
}

// ---------------- kernel 2: pqM[b][m] = (exp(am), exp(0.2*am)) ----------------
__global__ __launch_bounds__(256) void k_amac(const float* __restrict__ feat_mac,
        const float* __restrict__ mac_w, const float* __restrict__ mac_alpha,
        float2* __restrict__ pqM)
{
    __shared__ float partial[256];
    __shared__ float waS[64];
    int t = threadIdx.x;
    {
        int d = t & 63, seg = t >> 6;
        float p = 0.f;
        #pragma unroll 8
        for (int n = seg * 32; n < seg * 32 + 32; ++n)
            p = fmaf(mac_w[n * DIM + d], mac_alpha[n], p);
        partial[seg * 64 + d] = p;
    }
    __syncthreads();
    if (t < 64) waS[t] = partial[t] + partial[64 + t] + partial[128 + t] + partial[192 + t];
    __syncthreads();
    int row = blockIdx.x * 256 + t;                    // 32768 rows
    const float* fr = feat_mac + (size_t)row * DIM;
    float s = 0.f;
    #pragma unroll
    for (int k = 0; k < DIM; k += 4) {
        float4 v = *(const float4*)(fr + k);
        s = fmaf(v.x, waS[k], s); s = fmaf(v.y, waS[k + 1], s);
        s = fmaf(v.z, waS[k + 2], s); s = fmaf(v.w, waS[k + 3], s);
    }
    pqM[row] = make_float2(__expf(s), __expf(0.2f * s));
}

// ---------------- kernel 3: fused bitmask->softmax->MFMA + h_res ----------------
// 4 waves, 4-way K-split, even/odd m-pairing, broadcast uint4 bitmask loads.
__global__ __launch_bounds__(256) void k_attn(const unsigned* __restrict__ pk,
        const unsigned short* __restrict__ h_f,
        const float2* __restrict__ pq, const float2* __restrict__ pqM,
        const float* __restrict__ feat_mac, const float* __restrict__ res_w,
        float* __restrict__ out)
{
    int lin = blockIdx.x;                              // 1024
    int b   = 4 * (lin & 7) + ((lin >> 3) & 3);        // XCD k serves b in {4k..4k+3}
    int m0  = (lin >> 5) * 32;
    int t = threadIdx.x, wv = t >> 6, lane = t & 63;
    int L = lane & 15, q = lane >> 4;

    const unsigned* pkb = pk + ((size_t)b * 32 + (m0 >> 5)) * N_OPE;
    const unsigned short* hfb = h_f + (size_t)b * (64 * 8 * 64 * 8);
    const float2* pqb = pq + (size_t)b * N_OPE;

    float4 pm = *(const float4*)(pqM + (size_t)b * N_MAC + m0 + 2 * L);
    float pM0 = pm.x, qM0 = pm.y, pM1 = pm.z, qM1 = pm.w;

    floatx4 C0[8], C1[8];
    #pragma unroll
    for (int i = 0; i < 8; ++i) { C0[i] = (floatx4)0.f; C1[i] = (floatx4)0.f; }
    float den0 = 0.f, den1 = 0.f;

    int oBeg = wv * (N_OPE / 4);
    for (int o0 = oBeg; o0 < oBeg + N_OPE / 4; o0 += 32) {
        int ob = o0 + q * 8;
        float4 pv0 = *(const float4*)(pqb + ob);
        float4 pv1 = *(const float4*)(pqb + ob + 2);
        float4 pv2 = *(const float4*)(pqb + ob + 4);
        float4 pv3 = *(const float4*)(pqb + ob + 6);
        float pA[8] = {pv0.x, pv0.z, pv1.x, pv1.z, pv2.x, pv2.z, pv3.x, pv3.z};
        float qA[8] = {pv0.y, pv0.w, pv1.y, pv1.w, pv2.y, pv2.w, pv3.y, pv3.w};

        uint4 wk0 = *(const uint4*)(pkb + ob);         // words for rows ob..ob+3 (bcast over L)
        uint4 wk1 = *(const uint4*)(pkb + ob + 4);     // rows ob+4..ob+7
        unsigned wkv[8] = {wk0.x, wk0.y, wk0.z, wk0.w, wk1.x, wk1.y, wk1.z, wk1.w};

        const unsigned short* fp = hfb + (((size_t)(o0 >> 5) * 8) * 64 + lane) * 8;
        short8 Bf[8];
        #pragma unroll
        for (int nf = 0; nf < 8; ++nf)
            Bf[nf] = *(const short8*)(fp + (size_t)nf * 512);

        float w0v[8], w1v[8];
        #pragma unroll
        for (int j = 0; j < 8; ++j) {
            unsigned bits = wkv[j] >> (2 * L);
            float tp0 = pA[j] * pM0;
            float w0 = (tp0 >= 1.0f) ? tp0 : qA[j] * qM0;
            w0 = (bits & 1u) ? w0 : 0.f;
            den0 += w0; w0v[j] = w0;
            float tp1 = pA[j] * pM1;
            float w1 = (tp1 >= 1.0f) ? tp1 : qA[j] * qM1;
            w1 = (bits & 2u) ? w1 : 0.f;
            den1 += w1; w1v[j] = w1;
        }
        int4 A0i, A1i;
        #pragma unroll
        for (int j2 = 0; j2 < 4; ++j2) {
            unsigned lo0 = __builtin_bit_cast(unsigned, w0v[2 * j2])     + 0x8000u;
            unsigned hi0 = __builtin_bit_cast(unsigned, w0v[2 * j2 + 1]) + 0x8000u;
            ((unsigned*)&A0i)[j2] = __builtin_amdgcn_perm(hi0, lo0, 0x07060302u);
            unsigned lo1 = __builtin_bit_cast(unsigned, w1v[2 * j2])     + 0x8000u;
            unsigned hi1 = __builtin_bit_cast(unsigned, w1v[2 * j2 + 1]) + 0x8000u;
            ((unsigned*)&A1i)[j2] = __builtin_amdgcn_perm(hi1, lo1, 0x07060302u);
        }
        short8 A0 = __builtin_bit_cast(short8, A0i);
        short8 A1 = __builtin_bit_cast(short8, A1i);

        #pragma unroll
        for (int nf = 0; nf < 8; ++nf) {
            C0[nf] = __builtin_amdgcn_mfma_f32_16x16x32_bf16(A0, Bf[nf], C0[nf], 0, 0, 0);
            C1[nf] = __builtin_amdgcn_mfma_f32_16x16x32_bf16(A1, Bf[nf], C1[nf], 0, 0, 0);
        }
    }

    den0 += __shfl_xor(den0, 16); den0 += __shfl_xor(den0, 32);
    den1 += __shfl_xor(den1, 16); den1 += __shfl_xor(den1, 32);

    __shared__ float buf0[32 * 132];
    __shared__ float buf1[32 * 132];
    __shared__ float DS[4][32];
    if (q == 0) { DS[wv][L] = den0; DS[wv][16 + L] = den1; }

    if (wv == 0 || wv == 2) {
        float* bp = (wv == 0) ? buf0 : buf1;
        #pragma unroll
        for (int mf = 0; mf < 2; ++mf) {
            const floatx4* Cf = mf ? C1 : C0;
            #pragma unroll
            for (int nf = 0; nf < 8; ++nf)
                #pragma unroll
                for (int r = 0; r < 4; ++r)
                    bp[(mf * 16 + q * 4 + r) * 132 + nf * 16 + L] = Cf[nf][r];
        }
    }
    __syncthreads();
    if (wv == 1 || wv == 3) {
        float* bp = (wv == 1) ? buf0 : buf1;
        #pragma unroll
        for (int mf = 0; mf < 2; ++mf) {
            const floatx4* Cf = mf ? C1 : C0;
            #pragma unroll
            for (int nf = 0; nf < 8; ++nf)
                #pragma unroll
                for (int r = 0; r < 4; ++r)
                    bp[(mf * 16 + q * 4 + r) * 132 + nf * 16 + L] += Cf[nf][r];
        }
    }
    __syncthreads();

    // ---- inline h_res (3-term split MFMA); machine m = m0 + 2L + mf for A-frag mf
    float fA[2][2][8];
    #pragma unroll
    for (int mf = 0; mf < 2; ++mf) {
        const float* fr = feat_mac + ((size_t)b * N_MAC + m0 + 2 * L + mf) * DIM + q * 8;
        #pragma unroll
        for (int ks = 0; ks < 2; ++ks) {
            float4 v0 = *(const float4*)(fr + ks * 32);
            float4 v1 = *(const float4*)(fr + ks * 32 + 4);
            fA[mf][ks][0] = v0.x; fA[mf][ks][1] = v0.y; fA[mf][ks][2] = v0.z; fA[mf][ks][3] = v0.w;
            fA[mf][ks][4] = v1.x; fA[mf][ks][5] = v1.y; fA[mf][ks][6] = v1.z; fA[mf][ks][7] = v1.w;
        }
    }
    short8 Ah[2][2], Al[2][2];
    #pragma unroll
    for (int mf = 0; mf < 2; ++mf)
        #pragma unroll
        for (int ks = 0; ks < 2; ++ks)
            #pragma unroll
            for (int j = 0; j < 8; ++j) {
                float x = fA[mf][ks][j];
                unsigned short h = f2bf(x);
                Ah[mf][ks][j] = (short)h;
                Al[mf][ks][j] = (short)f2bf(x - bf2f(h));
            }
    floatx4 R[2][2];
    R[0][0] = (floatx4)0.f; R[0][1] = (floatx4)0.f;
    R[1][0] = (floatx4)0.f; R[1][1] = (floatx4)0.f;
    #pragma unroll
    for (int ks = 0; ks < 2; ++ks) {
        #pragma unroll
        for (int nfl = 0; nfl < 2; ++nfl) {
            const float* wp = res_w + (size_t)((wv * 2 + nfl) * 16 + L) * DIM + ks * 32 + q * 8;
            float4 u0 = *(const float4*)(wp);
            float4 u1 = *(const float4*)(wp + 4);
            float bw[8] = {u0.x, u0.y, u0.z, u0.w, u1.x, u1.y, u1.z, u1.w};
            short8 Bh, Bl;
            #pragma unroll
            for (int j = 0; j < 8; ++j) {
                unsigned short h = f2bf(bw[j]);
                Bh[j] = (short)h;
                Bl[j] = (short)f2bf(bw[j] - bf2f(h));
            }
            #pragma unroll
            for (int mf = 0; mf < 2; ++mf) {
                R[mf][nfl] = __builtin_amdgcn_mfma_f32_16x16x32_bf16(Ah[mf][ks], Bh, R[mf][nfl], 0, 0, 0);
                R[mf][nfl] = __builtin_amdgcn_mfma_f32_16x16x32_bf16(Al[mf][ks], Bh, R[mf][nfl], 0, 0, 0);
                R[mf][nfl] = __builtin_amdgcn_mfma_f32_16x16x32_bf16(Ah[mf][ks], Bl, R[mf][nfl], 0, 0, 0);
            }
        }
    }

    #pragma unroll
    for (int mf = 0; mf < 2; ++mf) {
        #pragma unroll
        for (int r = 0; r < 4; ++r) {
            int fragrow = q * 4 + r;
            int m = m0 + 2 * fragrow + mf;
            float inv = 1.0f / (DS[0][mf * 16 + fragrow] + DS[1][mf * 16 + fragrow]
                              + DS[2][mf * 16 + fragrow] + DS[3][mf * 16 + fragrow]);
            size_t obase = ((size_t)b * N_MAC + m) * KOUT;
            #pragma unroll
            for (int nfl = 0; nfl < 2; ++nfl) {
                int col = (wv * 2 + nfl) * 16 + L;
                float num = buf0[(mf * 16 + fragrow) * 132 + col]
                          + buf1[(mf * 16 + fragrow) * 132 + col];
                out[obase + col] = num * inv + R[mf][nfl][r];
            }
        }
    }
}

extern "C" void kernel_launch(void* const* d_in, const int* in_sizes, int n_in,
                              void* d_out, int out_size, void* d_ws, size_t ws_size,
                              hipStream_t stream) {
    const int*   adj       = (const int*)d_in[0];
    const int*   bidx      = (const int*)d_in[1];
    const float* feat_ope  = (const float*)d_in[2];
    const float* feat_mac  = (const float*)d_in[3];
    const float* ope_w     = (const float*)d_in[4];
    const float* mac_w     = (const float*)d_in[5];
    const float* ope_alpha = (const float*)d_in[6];
    const float* mac_alpha = (const float*)d_in[7];
    const float* res_w     = (const float*)d_in[8];
    float* out = (float*)d_out;

    char* ws = (char*)d_ws;
    unsigned short* h_f = (unsigned short*)ws;                              // 16 MiB
    float2* pq          = (float2*)(ws + (size_t)(16 << 20));               // 512 KiB
    float2* pqM         = (float2*)(ws + (size_t)(16 << 20) + (512 << 10)); // 256 KiB
    unsigned* pk        = (unsigned*)(ws + (size_t)(17 << 20));             // 8 MiB

    k_pack<<<1024, 256, 0, stream>>>(adj, bidx, pk);
    k_ope<<<512, 256, 0, stream>>>(feat_ope, ope_w, ope_alpha, h_f, pq);
    k_amac<<<128, 256, 0, stream>>>(feat_mac, mac_w, mac_alpha, pqM);
    k_attn<<<1024, 256, 0, stream>>>(pk, h_f, pq, pqM, feat_mac, res_w, out);
}